// Round 2
// baseline (8183.997 us; speedup 1.0000x reference)
//
#include <hip/hip_runtime.h>
#include <stdint.h>

typedef unsigned short u16;
typedef short short8 __attribute__((ext_vector_type(8)));
typedef float f32x4 __attribute__((ext_vector_type(4)));
typedef unsigned int u32x4 __attribute__((ext_vector_type(4)));

#define NS 256
#define CIN 2304
#define CH 512
#define HW 49
#define MTOT (NS*HW)   // 12544

__device__ __forceinline__ float b2f(u16 u){
    union { unsigned int v; float f; } x; x.v = ((unsigned int)u) << 16; return x.f;
}
__device__ __forceinline__ u16 f2b(float f){
    unsigned int u = __builtin_bit_cast(unsigned int, f);
    u += 0x7FFFu + ((u >> 16) & 1u);
    return (u16)(u >> 16);
}
__device__ __forceinline__ u16 load_as_bf16(const void* p, size_t i, int isf32){
    return isf32 ? f2b(((const float*)p)[i]) : ((const u16*)p)[i];
}

// ---------------- dtype detector: fp32 mantissa halves have big exponents ----
__global__ void k_detect(const u16* __restrict__ src, int* __restrict__ flag){
    int cnt = 0;
    for (int i = threadIdx.x; i < 8192; i += 256){
        int e = (src[i] >> 7) & 0xFF;
        cnt += (e >= 0x90);
    }
    for (int off = 32; off; off >>= 1) cnt += __shfl_down(cnt, off, 64);
    __shared__ int sh[4];
    int wave = threadIdx.x >> 6, lane = threadIdx.x & 63;
    if (lane == 0) sh[wave] = cnt;
    __syncthreads();
    if (threadIdx.x == 0)
        flag[0] = (sh[0] + sh[1] + sh[2] + sh[3] > 200) ? 1 : 0;
}

// ---------------- small converter (to bf16) ----------------------------------
__global__ void k_convert_small(const void* __restrict__ src, u16* __restrict__ dst,
                                int n, const int* __restrict__ flag){
    const int isf32 = flag[0];
    for (int i = blockIdx.x*256 + threadIdx.x; i < n; i += gridDim.x*256)
        dst[i] = load_as_bf16(src, i, isf32);
}

// ---------------- transpose bbox_feat [n][2304][49] -> in_t [n][49][2304] ----
__global__ void k_transpose_in(const void* __restrict__ src, u16* __restrict__ dst,
                               const int* __restrict__ flag){
    const int isf32 = flag[0];
    __shared__ u16 tile[64*50];
    const int n = blockIdx.x;
    const int c0 = blockIdx.y * 64;
    const size_t sbase = ((size_t)n*CIN + c0)*HW;
    for (int idx = threadIdx.x; idx < 64*49; idx += 256){
        int cc = idx / 49, hw = idx - cc*49;
        tile[cc*50 + hw] = load_as_bf16(src, sbase + cc*HW + hw, isf32);
    }
    __syncthreads();
    u16* d = dst + (size_t)n*HW*CIN + c0;
    for (int idx = threadIdx.x; idx < 49*64; idx += 256){
        int hw = idx >> 6, cc = idx & 63;
        d[(size_t)hw*CIN + cc] = tile[cc*50 + hw];
    }
}

// ---------------- weight transpose [512][Cin][9] -> [512][9][Cin] ------------
__global__ void k_transpose_w(const void* __restrict__ w, u16* __restrict__ wt,
                              int Cin, const int* __restrict__ flag){
    const int isf32 = flag[0];
    size_t total = (size_t)CH * Cin * 9;
    for (size_t d = (size_t)blockIdx.x*blockDim.x + threadIdx.x; d < total;
         d += (size_t)gridDim.x*blockDim.x){
        int c  = (int)(d % Cin);
        size_t t = d / Cin;
        int kk = (int)(t % 9);
        int co = (int)(t / 9);
        wt[d] = load_as_bf16(w, ((size_t)co*Cin + c)*9 + kk, isf32);
    }
}

// ---------------- generic 3x3 pad-1 conv as implicit GEMM (MFMA) -------------
// mode 0: out_cl[m][co] = acc (bf16)
// mode 1: out[branch][n][co][hw] = acc + feat_res[m][co], dtype per dtf
__global__ __launch_bounds__(256) void k_conv3x3(
        const u16* __restrict__ in_t, const u16* __restrict__ w_t, int Cin,
        u16* __restrict__ out_cl,
        const u16* __restrict__ feat_res, void* __restrict__ out_base,
        int mode, int branch, const int* __restrict__ dtf)
{
    __shared__ __align__(16) u16 As[128*32];
    __shared__ __align__(16) u16 Bs[128*32];
    const int tid  = threadIdx.x;
    const int wave = tid >> 6, lane = tid & 63;
    const int m0  = blockIdx.x * 128;
    const int co0 = blockIdx.y * 128;

    int rA[2], nA[2], yA[2], xA[2], koA[2], coB[2];
    for (int s = 0; s < 2; ++s){
        int seg = tid + s*256;
        int r = seg >> 2, ko = seg & 3;
        rA[s] = r; koA[s] = ko;
        int m = m0 + r;
        nA[s] = m / 49;
        int hw = m - nA[s]*49;
        yA[s] = hw / 7; xA[s] = hw - yA[s]*7;
        coB[s] = co0 + r;
    }

    f32x4 acc[4][4];
    for (int i = 0; i < 4; ++i)
        for (int j = 0; j < 4; ++j)
            acc[i][j] = (f32x4){0.f, 0.f, 0.f, 0.f};

    const int wm = (wave & 1) * 64, wn = (wave >> 1) * 64;
    int aoff[4], boff[4];
    for (int i = 0; i < 4; ++i){
        aoff[i] = (wm + i*16 + (lane & 15))*32 + (lane >> 4)*8;
        boff[i] = (wn + i*16 + (lane & 15))*32 + (lane >> 4)*8;
    }

    const u32x4 vzero = {0u, 0u, 0u, 0u};
    for (int kk = 0; kk < 9; ++kk){
        const int dy = kk/3 - 1, dx = kk - (kk/3)*3 - 1;
        const u16* srcA[2];
        const u16* srcB[2];
        for (int s = 0; s < 2; ++s){
            int yy = yA[s] + dy, xx = xA[s] + dx;
            bool valid = (yy >= 0) & (yy < 7) & (xx >= 0) & (xx < 7);
            srcA[s] = valid ? in_t + ((size_t)(nA[s]*49 + yy*7 + xx))*Cin + koA[s]*8
                            : nullptr;
            srcB[s] = w_t + ((size_t)coB[s]*9 + kk)*Cin + koA[s]*8;
        }
        for (int c0 = 0; c0 < Cin; c0 += 32){
            u32x4 va[2], vb[2];
            for (int s = 0; s < 2; ++s){
                va[s] = srcA[s] ? *(const u32x4*)(srcA[s] + c0) : vzero;
                vb[s] = *(const u32x4*)(srcB[s] + c0);
            }
            __syncthreads();
            for (int s = 0; s < 2; ++s){
                *(u32x4*)(&As[rA[s]*32 + koA[s]*8]) = va[s];
                *(u32x4*)(&Bs[(coB[s] - co0)*32 + koA[s]*8]) = vb[s];
            }
            __syncthreads();
            short8 af[4], bfr[4];
            for (int i = 0; i < 4; ++i) af[i]  = *(const short8*)(&As[aoff[i]]);
            for (int j = 0; j < 4; ++j) bfr[j] = *(const short8*)(&Bs[boff[j]]);
            for (int i = 0; i < 4; ++i)
                for (int j = 0; j < 4; ++j)
                    acc[i][j] = __builtin_amdgcn_mfma_f32_16x16x32_bf16(
                                    af[i], bfr[j], acc[i][j], 0, 0, 0);
        }
    }

    const int isf32 = (mode == 1) ? dtf[0] : 0;
    for (int i = 0; i < 4; ++i){
        int mbase = m0 + wm + i*16 + (lane >> 4)*4;
        for (int j = 0; j < 4; ++j){
            int co = co0 + wn + j*16 + (lane & 15);
            for (int r = 0; r < 4; ++r){
                int m = mbase + r;
                float v = acc[i][j][r];
                if (mode == 0){
                    out_cl[(size_t)m*CH + co] = f2b(v);
                } else {
                    float res = b2f(feat_res[(size_t)m*CH + co]);
                    int n = m / 49, hw = m - (m/49)*49;
                    size_t off = (size_t)branch*MTOT*CH + ((size_t)n*CH + co)*HW + hw;
                    float o = v + res;
                    if (isf32) ((float*)out_base)[off] = o;
                    else       ((u16*)out_base)[off]   = f2b(o);
                }
            }
        }
    }
}

// ---------------- q conv: spatially-constant 5-ch input ----------------------
__global__ void k_qconv(const u16* __restrict__ status, const u16* __restrict__ rois,
                        const u16* __restrict__ wq, u16* __restrict__ q_t, int branch){
    const int n = blockIdx.x, hw = blockIdx.y;
    const int co = threadIdx.x;          // 512 threads
    const int y = hw / 7, x = hw - (hw/7)*7;
    float sval[5];
    sval[0] = b2f(status[n*2 + branch]);
    for (int c = 1; c < 5; ++c) sval[c] = b2f(rois[n*5 + c]);
    float acc = 0.f;
    for (int c = 0; c < 5; ++c){
        float wsum = 0.f;
        for (int ky = 0; ky < 3; ++ky){
            int yy = y + ky - 1; if (yy < 0 || yy >= 7) continue;
            for (int kx = 0; kx < 3; ++kx){
                int xx = x + kx - 1; if (xx < 0 || xx >= 7) continue;
                wsum += b2f(wq[(co*5 + c)*9 + ky*3 + kx]);
            }
        }
        acc += sval[c] * wsum;
    }
    q_t[((size_t)n*HW + hw)*CH + co] = f2b(acc);
}

// ---------------- attention per (g, hw) --------------------------------------
__global__ void k_att(const u16* __restrict__ q_t, const u16* __restrict__ k_t,
                      const u16* __restrict__ v_t, u16* __restrict__ virt_t){
    __shared__ u16 qs[16*520], ks[16*520], vs[16*520];
    __shared__ float ls[256], ps[256];
    const int hw = blockIdx.x, g = blockIdx.y;
    const int tid = threadIdx.x;
    for (int idx = tid; idx < 16*512; idx += 256){
        int i = idx >> 9, c = idx & 511;
        size_t m = (size_t)(g*16 + i)*HW + hw;
        qs[i*520 + c] = q_t[m*CH + c];
        ks[i*520 + c] = k_t[m*CH + c];
        vs[i*520 + c] = v_t[m*CH + c];
    }
    __syncthreads();
    const int i = tid >> 4, j = tid & 15;
    float dot = 0.f;
    for (int c = 0; c < 512; ++c) dot += b2f(qs[i*520 + c]) * b2f(ks[j*520 + c]);
    ls[tid] = dot * 0.04419417382415922f;   // 1/sqrt(512)
    __syncthreads();
    float mx = -1e30f;
    for (int jj = 0; jj < 16; ++jj) mx = fmaxf(mx, ls[i*16 + jj]);
    float ssum = 0.f;
    for (int jj = 0; jj < 16; ++jj) ssum += __expf(ls[i*16 + jj] - mx);
    ps[tid] = __expf(ls[tid] - mx) / ssum;
    __syncthreads();
    const int c0 = tid & 15, ii = tid >> 4;
    for (int c = c0; c < 512; c += 16){
        float a = 0.f;
        for (int jj = 0; jj < 16; ++jj) a += ps[ii*16 + jj] * b2f(vs[jj*520 + c]);
        virt_t[((size_t)(g*16 + ii)*HW + hw)*CH + c] = f2b(a);
    }
}

// ---------------- per-sample mean/rstd over 512*49 ---------------------------
__global__ void k_stats(const u16* __restrict__ virt_t, float* __restrict__ stats){
    const int n = blockIdx.x;
    const u16* p = virt_t + (size_t)n * (CH*HW);
    float s = 0.f, s2 = 0.f;
    for (int idx = threadIdx.x; idx < CH*HW; idx += 256){
        float v = b2f(p[idx]); s += v; s2 += v*v;
    }
    for (int off = 32; off; off >>= 1){
        s  += __shfl_down(s,  off, 64);
        s2 += __shfl_down(s2, off, 64);
    }
    __shared__ float bs[4], bs2[4];
    int wave = threadIdx.x >> 6, lane = threadIdx.x & 63;
    if (lane == 0){ bs[wave] = s; bs2[wave] = s2; }
    __syncthreads();
    if (threadIdx.x == 0){
        float t = 0.f, t2 = 0.f;
        for (int w = 0; w < 4; ++w){ t += bs[w]; t2 += bs2[w]; }
        float mean = t / (float)(CH*HW);
        float var  = t2 / (float)(CH*HW) - mean*mean;
        stats[n*2]   = mean;
        stats[n*2+1] = rsqrtf(var + 1e-5f);
    }
}

// ---------------- normalize + relu ------------------------------------------
__global__ void k_norm(const u16* __restrict__ virt_t, const float* __restrict__ stats,
                       const u16* __restrict__ gamma, const u16* __restrict__ beta,
                       u16* __restrict__ h_t){
    size_t idx = (size_t)blockIdx.x*256 + threadIdx.x;
    if (idx >= (size_t)NS*HW*CH) return;
    int c = (int)(idx & 511);
    int m = (int)(idx >> 9);
    int n = m / 49;
    float v = b2f(virt_t[idx]);
    float h = (v - stats[n*2]) * stats[n*2+1] * b2f(gamma[c]) + b2f(beta[c]);
    h_t[idx] = f2b(fmaxf(h, 0.f));
}

extern "C" void kernel_launch(void* const* d_in, const int* in_sizes, int n_in,
                              void* d_out, int out_size, void* d_ws, size_t ws_size,
                              hipStream_t stream) {
    const void* status   = d_in[0];
    const void* rois     = d_in[1];
    const void* bbox     = d_in[2];
    const void* w_reduce = d_in[3];
    const void* w_q1     = d_in[4];
    const void* w_q2     = d_in[5];
    const void* w_k1     = d_in[6];
    const void* w_v1     = d_in[7];
    const void* w_k2     = d_in[8];
    const void* w_v2     = d_in[9];
    const void* w_c1     = d_in[10];
    const void* w_c2     = d_in[11];
    const void* gamma    = d_in[12];
    const void* beta     = d_in[13];

    // ---- workspace layout with aliasing (total ~120.4 MB) ----
    char* p = (char*)d_ws;
    const size_t SZ_INT  = (size_t)MTOT*CIN*2;   // 57,802,752  region0
    const size_t SZ_WRT  = (size_t)CH*9*CIN*2;   // 21,233,664  region1
    const size_t SZ_T    = (size_t)MTOT*CH*2;    // 12,845,056
    const size_t SZ_WT   = (size_t)CH*9*CH*2;    //  4,718,592

    u16* in_t  = (u16*)p;
    u16* w_r_t = (u16*)(p + SZ_INT);
    char* p2   = p + SZ_INT + SZ_WRT;
    u16* wt[6];
    for (int i = 0; i < 6; ++i) wt[i] = (u16*)(p2 + i*SZ_WT);
    u16* feat_t = (u16*)(p2 + 6*SZ_WT);
    char* p3 = p2 + 6*SZ_WT + SZ_T;
    float* stats    = (float*)p3;
    int*   flag     = (int*)(p3 + 4096);
    u16*   status_c = (u16*)(p3 + 8192);
    u16*   rois_c   = status_c + 1024;
    u16*   gamma_c  = rois_c + 2048;
    u16*   beta_c   = gamma_c + 512;
    u16*   wq_c0    = beta_c + 512;
    u16*   wq_c1    = wq_c0 + CH*5*9;
    // aliases into regions dead after the feat conv:
    u16* q_t    = (u16*)p;
    u16* k_t    = (u16*)(p + SZ_T);
    u16* v_t    = (u16*)(p + 2*SZ_T);
    u16* virt_t = (u16*)(p + 3*SZ_T);   // 4*SZ_T = 51.4MB <= 57.8MB
    u16* h_t    = w_r_t;                // 12.85MB <= 21.2MB

    k_detect<<<1, 256, 0, stream>>>((const u16*)bbox, flag);
    k_transpose_in<<<dim3(NS, CIN/64), 256, 0, stream>>>(bbox, in_t, flag);
    k_transpose_w<<<1024, 256, 0, stream>>>(w_reduce, w_r_t, CIN, flag);
    const void* wsrc[6] = {w_k1, w_v1, w_k2, w_v2, w_c1, w_c2};
    for (int i = 0; i < 6; ++i)
        k_transpose_w<<<512, 256, 0, stream>>>(wsrc[i], wt[i], CH, flag);
    k_convert_small<<<2, 256, 0, stream>>>(status, status_c, NS*2, flag);
    k_convert_small<<<5, 256, 0, stream>>>(rois, rois_c, NS*5, flag);
    k_convert_small<<<2, 256, 0, stream>>>(gamma, gamma_c, CH, flag);
    k_convert_small<<<2, 256, 0, stream>>>(beta, beta_c, CH, flag);
    k_convert_small<<<90, 256, 0, stream>>>(w_q1, wq_c0, CH*5*9, flag);
    k_convert_small<<<90, 256, 0, stream>>>(w_q2, wq_c1, CH*5*9, flag);

    k_conv3x3<<<dim3(MTOT/128, CH/128), 256, 0, stream>>>(
        in_t, w_r_t, CIN, feat_t, nullptr, nullptr, 0, 0, flag);

    for (int br = 0; br < 2; ++br){
        k_qconv<<<dim3(NS, HW), 512, 0, stream>>>(status_c, rois_c,
                                                  br ? wq_c1 : wq_c0, q_t, br);
        k_conv3x3<<<dim3(MTOT/128, CH/128), 256, 0, stream>>>(
            feat_t, wt[br*2 + 0], CH, k_t, nullptr, nullptr, 0, 0, flag);
        k_conv3x3<<<dim3(MTOT/128, CH/128), 256, 0, stream>>>(
            feat_t, wt[br*2 + 1], CH, v_t, nullptr, nullptr, 0, 0, flag);
        k_att<<<dim3(HW, 16), 256, 0, stream>>>(q_t, k_t, v_t, virt_t);
        k_stats<<<NS, 256, 0, stream>>>(virt_t, stats);
        k_norm<<<(NS*HW*CH)/256, 256, 0, stream>>>(virt_t, stats, gamma_c, beta_c, h_t);
        k_conv3x3<<<dim3(MTOT/128, CH/128), 256, 0, stream>>>(
            h_t, wt[4 + br], CH, nullptr, feat_t, d_out, 1, br, flag);
    }
}